// Round 7
// baseline (381.107 us; speedup 1.0000x reference)
//
#include <hip/hip_runtime.h>
#include <hip/hip_bf16.h>
#include <stdint.h>

typedef uint16_t u16;
typedef __bf16 bf16x8 __attribute__((ext_vector_type(8)));
typedef float f32x4 __attribute__((ext_vector_type(4)));
typedef u16 u16x4 __attribute__((ext_vector_type(4)));
typedef uint32_t u32x2 __attribute__((ext_vector_type(2)));

#define S_LEN 2048
#define D_MODEL 4096
#define N_HEADS 32
#define N_KVH 8
#define HEAD_DIM 128
#define QD 4096   // N_HEADS*HEAD_DIM
#define KVD 1024  // N_KVH*HEAD_DIM
#define KVS 2048  // fused K|V row stride

// softmax: P = exp2(t - M2), t = (q.k)*scale*log2e (scale*log2e folded into Q)
#define QSC 0.1275253958595506f   // (1/sqrt(128)) * log2(e)
#define M2F 16.0f                 // fixed bound in log2 units; |t| <= ~9

typedef __attribute__((address_space(3))) uint8_t lds_u8;
typedef const __attribute__((address_space(1))) uint8_t glb_u8;

__device__ __forceinline__ float bf2f(u16 x) {
    union { unsigned u; float f; } c; c.u = ((unsigned)x) << 16; return c.f;
}
__device__ __forceinline__ u16 f2bf(float f) {
    union { float f; unsigned u; } c; c.f = f;
    unsigned u = c.u;
    u += 0x7fffu + ((u >> 16) & 1u);
    return (u16)(u >> 16);
}
__device__ __forceinline__ uint32_t cvt_pk_bf16(float a, float b) {
    uint32_t r;
    asm("v_cvt_pk_bf16_f32 %0, %1, %2" : "=v"(r) : "v"(a), "v"(b));
    return r;
}

// ---------------- f32 -> bf16 convert (vectorized x4) ----------------
__global__ __launch_bounds__(256) void conv_f2b_kernel(
    const float* __restrict__ in, u16* __restrict__ out, int n4)
{
    int i = blockIdx.x * blockDim.x + threadIdx.x;
    if (i < n4) {
        float4 v = ((const float4*)in)[i];
        u16x4 o;
        o.x = f2bf(v.x); o.y = f2bf(v.y); o.z = f2bf(v.z); o.w = f2bf(v.w);
        ((u16x4*)out)[i] = o;
    }
}

// ---------------- transpose+convert: in f32 (R,C) -> out bf16 (C,R) ----------------
__global__ __launch_bounds__(256) void transpose_f2b_kernel(
    const float* __restrict__ in, u16* __restrict__ out, int R, int C)
{
    __shared__ u16 tile[32][33];
    const int cb = blockIdx.x * 32;
    const int rb = blockIdx.y * 32;
    const int tx = threadIdx.x;       // 0..31
    const int ty0 = threadIdx.y;      // 0..7
#pragma unroll
    for (int i = 0; i < 4; ++i) {
        int ty = ty0 + i * 8;
        tile[ty][tx] = f2bf(in[(size_t)(rb + ty) * C + cb + tx]);
    }
    __syncthreads();
#pragma unroll
    for (int i = 0; i < 4; ++i) {
        int ty = ty0 + i * 8;
        out[(size_t)(cb + ty) * R + rb + tx] = tile[tx][ty];
    }
}

// ---------------- transpose bf16 (R,C) -> (C,R), input row stride ld ----------------
__global__ __launch_bounds__(256) void transpose_kernel(
    const u16* __restrict__ in, u16* __restrict__ out, int R, int C, int ld)
{
    __shared__ u16 tile[32][33];
    const int cb = blockIdx.x * 32;
    const int rb = blockIdx.y * 32;
    const int tx = threadIdx.x;
    const int ty0 = threadIdx.y;
#pragma unroll
    for (int i = 0; i < 4; ++i) {
        int ty = ty0 + i * 8;
        tile[ty][tx] = in[(size_t)(rb + ty) * ld + cb + tx];
    }
    __syncthreads();
#pragma unroll
    for (int i = 0; i < 4; ++i) {
        int ty = ty0 + i * 8;
        out[(size_t)(cb + ty) * R + rb + tx] = tile[tx][ty];
    }
}

// ---------------- GEMM 128x128 (4 waves): C = A @ BT^T, bf16 in, fp32 acc ----------------
#define BM 128
#define BN 128
#define BKK 64

template <typename OT>
__global__ __launch_bounds__(256) void gemm_bt_kernel(
    const u16* __restrict__ A, const u16* __restrict__ BT, OT* __restrict__ C,
    int M, int N, int K)
{
    __shared__ u16 sA[2][BM * BKK];
    __shared__ u16 sB[2][BN * BKK];
    const int nbx = N / BN;
    const int bx = blockIdx.x % nbx;
    const int by = blockIdx.x / nbx;
    const int row0 = by * BM, col0 = bx * BN;
    const int t = threadIdx.x;
    const int w = t >> 6, l = t & 63;
    const int wr = w >> 1, wc = w & 1;
    const int l16 = l & 15, lk = l >> 4;

    f32x4 acc[4][4] = {};

    auto stage = [&](int buf, int k0) {
#pragma unroll
        for (int j = 0; j < 4; ++j) {
            int chunk = j * 256 + w * 64 + l;
            int r = chunk >> 3;
            int pc = chunk & 7;
            int gch = pc ^ (r & 7);
            const u16* ga = A  + (size_t)(row0 + r) * K + k0 + gch * 8;
            const u16* gb = BT + (size_t)(col0 + r) * K + k0 + gch * 8;
            __builtin_amdgcn_global_load_lds((glb_u8*)ga,
                (lds_u8*)(sA[buf] + (size_t)(j * 256 + w * 64) * 8), 16, 0, 0);
            __builtin_amdgcn_global_load_lds((glb_u8*)gb,
                (lds_u8*)(sB[buf] + (size_t)(j * 256 + w * 64) * 8), 16, 0, 0);
        }
    };

    stage(0, 0);
    int cur = 0;
    for (int k0 = 0; k0 < K; k0 += BKK) {
        __syncthreads();   // drains vmcnt -> buf[cur] resident; prior reads done
        if (k0 + BKK < K) stage(cur ^ 1, k0 + BKK);
        const u16* cA = sA[cur];
        const u16* cB = sB[cur];
#pragma unroll
        for (int kk = 0; kk < 2; ++kk) {
            bf16x8 af[4], bfr[4];
#pragma unroll
            for (int m = 0; m < 4; ++m) {
                int r = wr * 64 + m * 16 + l16;
                int ch = (kk * 4 + lk) ^ (r & 7);
                af[m] = *(const bf16x8*)(cA + r * BKK + ch * 8);
            }
#pragma unroll
            for (int n = 0; n < 4; ++n) {
                int r = wc * 64 + n * 16 + l16;
                int ch = (kk * 4 + lk) ^ (r & 7);
                bfr[n] = *(const bf16x8*)(cB + r * BKK + ch * 8);
            }
            __builtin_amdgcn_s_setprio(1);
#pragma unroll
            for (int m = 0; m < 4; ++m)
#pragma unroll
                for (int n = 0; n < 4; ++n)
                    acc[m][n] = __builtin_amdgcn_mfma_f32_16x16x32_bf16(
                        af[m], bfr[n], acc[m][n], 0, 0, 0);
            __builtin_amdgcn_s_setprio(0);
        }
        cur ^= 1;
    }
#pragma unroll
    for (int m = 0; m < 4; ++m)
#pragma unroll
        for (int n = 0; n < 4; ++n)
#pragma unroll
            for (int j = 0; j < 4; ++j) {
                int row = row0 + wr * 64 + m * 16 + lk * 4 + j;
                int col = col0 + wc * 64 + n * 16 + l16;
                if constexpr (sizeof(OT) == 2)
                    C[(size_t)row * N + col] = f2bf(acc[m][n][j]);
                else
                    C[(size_t)row * N + col] = acc[m][n][j];
            }
}

// ---------------- GEMM 128x256 (8 waves, counted-vmcnt pipeline) ----------------
// Raw s_barrier + s_waitcnt vmcnt(6): the 6 next-tile loads/wave stay in flight
// across the whole iteration; current tile's loads had a full iteration to land.
#define BMW 128
#define BNW 256
#define BKW 64

template <typename OT>
__global__ __launch_bounds__(512) void gemm_wide_kernel(
    const u16* __restrict__ A, const u16* __restrict__ BT, OT* __restrict__ C,
    int M, int N, int K)
{
    __shared__ u16 sA[2][BMW * BKW];   // 16 KB each
    __shared__ u16 sB[2][BNW * BKW];   // 32 KB each
    // bijective XCD swizzle (gridDim.x % 8 == 0): each XCD gets contiguous chunk
    const int wgid = (blockIdx.x & 7) * (gridDim.x >> 3) + (blockIdx.x >> 3);
    const int nbx = N / BNW;
    const int bx = wgid % nbx;
    const int by = wgid / nbx;
    const int row0 = by * BMW, col0 = bx * BNW;
    const int t = threadIdx.x;
    const int w = t >> 6, l = t & 63;
    const int wr = w >> 2, wc = w & 3;         // 2 x 4 waves, each owns 64x64
    const int l16 = l & 15, lk = l >> 4;

    f32x4 acc[4][4] = {};

    auto stage = [&](int buf, int k0) {
        // A: 1024 chunks of 16B -> 2 per thread
#pragma unroll
        for (int j = 0; j < 2; ++j) {
            int chunk = j * 512 + w * 64 + l;
            int r = chunk >> 3;
            int pc = chunk & 7;
            int gch = pc ^ (r & 7);
            const u16* ga = A + (size_t)(row0 + r) * K + k0 + gch * 8;
            __builtin_amdgcn_global_load_lds((glb_u8*)ga,
                (lds_u8*)(sA[buf] + (size_t)(j * 512 + w * 64) * 8), 16, 0, 0);
        }
        // B: 2048 chunks -> 4 per thread
#pragma unroll
        for (int j = 0; j < 4; ++j) {
            int chunk = j * 512 + w * 64 + l;
            int r = chunk >> 3;
            int pc = chunk & 7;
            int gch = pc ^ (r & 7);
            const u16* gb = BT + (size_t)(col0 + r) * K + k0 + gch * 8;
            __builtin_amdgcn_global_load_lds((glb_u8*)gb,
                (lds_u8*)(sB[buf] + (size_t)(j * 512 + w * 64) * 8), 16, 0, 0);
        }
    };

    stage(0, 0);
    int cur = 0;
    for (int k0 = 0; k0 < K; k0 += BKW) {
        if (k0 + BKW < K) {
            stage(cur ^ 1, k0 + BKW);
            asm volatile("s_waitcnt vmcnt(6)" ::: "memory");  // cur's 6 loads retired
        } else {
            asm volatile("s_waitcnt vmcnt(0)" ::: "memory");
        }
        __builtin_amdgcn_s_barrier();       // all waves' cur-loads certified
        __builtin_amdgcn_sched_barrier(0);
        const u16* cA = sA[cur];
        const u16* cB = sB[cur];
#pragma unroll
        for (int kk = 0; kk < 2; ++kk) {
            bf16x8 af[4], bfr[4];
#pragma unroll
            for (int m = 0; m < 4; ++m) {
                int r = wr * 64 + m * 16 + l16;
                int ch = (kk * 4 + lk) ^ (r & 7);
                af[m] = *(const bf16x8*)(cA + r * BKW + ch * 8);
            }
#pragma unroll
            for (int n = 0; n < 4; ++n) {
                int r = wc * 64 + n * 16 + l16;
                int ch = (kk * 4 + lk) ^ (r & 7);
                bfr[n] = *(const bf16x8*)(cB + r * BKW + ch * 8);
            }
            __builtin_amdgcn_s_setprio(1);
#pragma unroll
            for (int m = 0; m < 4; ++m)
#pragma unroll
                for (int n = 0; n < 4; ++n)
                    acc[m][n] = __builtin_amdgcn_mfma_f32_16x16x32_bf16(
                        af[m], bfr[n], acc[m][n], 0, 0, 0);
            __builtin_amdgcn_s_setprio(0);
        }
        __builtin_amdgcn_sched_barrier(0);
        __builtin_amdgcn_s_barrier();       // reads of buf[cur] done before overwrite
        cur ^= 1;
    }
#pragma unroll
    for (int m = 0; m < 4; ++m)
#pragma unroll
        for (int n = 0; n < 4; ++n)
#pragma unroll
            for (int j = 0; j < 4; ++j) {
                int row = row0 + wr * 64 + m * 16 + lk * 4 + j;
                int col = col0 + wc * 64 + n * 16 + l16;
                if constexpr (sizeof(OT) == 2)
                    C[(size_t)row * N + col] = f2bf(acc[m][n][j]);
                else
                    C[(size_t)row * N + col] = acc[m][n][j];
            }
}

// ---------------- RoPE cos/sin table: (S,64) fp32 each ----------------
__global__ void rope_table_kernel(const int* __restrict__ pos,
                                  float* __restrict__ ctab, float* __restrict__ stab)
{
    int s = blockIdx.x;
    int i = threadIdx.x; // 0..63
    float p = (float)pos[s];
    float freq = __expf(-(float)i * (9.210340371976184f / 64.0f)); // 10000^(-i/64)
    float ang = p * freq;
    ctab[s * 64 + i] = cosf(ang);
    stab[s * 64 + i] = sinf(ang);
}

// ---------------- RoPE apply for K (in place, bf16, no scale) ----------------
__global__ void rope_apply_k_kernel(u16* __restrict__ X,
                                    const float* __restrict__ ctab, const float* __restrict__ stab)
{
    int s = blockIdx.x;
    int t = threadIdx.x;
    int head = t >> 5;
    int j = t & 31;
    size_t base = (size_t)s * KVS + head * 128;
    float x1 = bf2f(X[base + j]);
    float x2 = bf2f(X[base + j + 32]);
    float c1 = ctab[s * 64 + j],      s1 = stab[s * 64 + j];
    float c2 = ctab[s * 64 + j + 32], s2 = stab[s * 64 + j + 32];
    X[base + j]      = f2bf(x1 * c1 - x2 * s1);
    X[base + j + 32] = f2bf(x2 * c2 + x1 * s2);
}

// ---------------- RoPE apply for Q: rotate + fold in scale*log2e on all 128 dims ----------------
__global__ void rope_apply_q_kernel(u16* __restrict__ X,
                                    const float* __restrict__ ctab, const float* __restrict__ stab)
{
    int s = blockIdx.x;
    int t = threadIdx.x;
    int head = t >> 5;
    int j = t & 31;
    size_t base = (size_t)s * QD + head * 128;
    float x1 = bf2f(X[base + j]);
    float x2 = bf2f(X[base + j + 32]);
    float c1 = ctab[s * 64 + j],      s1 = stab[s * 64 + j];
    float c2 = ctab[s * 64 + j + 32], s2 = stab[s * 64 + j + 32];
    X[base + j]      = f2bf((x1 * c1 - x2 * s1) * QSC);
    X[base + j + 32] = f2bf((x2 * c2 + x1 * s2) * QSC);
    float x3 = bf2f(X[base + j + 64]);
    float x4 = bf2f(X[base + j + 96]);
    X[base + j + 64] = f2bf(x3 * QSC);
    X[base + j + 96] = f2bf(x4 * QSC);
}

// ---------------- flash attention ----------------
__global__ __launch_bounds__(256) void attn_kernel(
    const u16* __restrict__ Q, const u16* __restrict__ Km, const u16* __restrict__ VT,
    u16* __restrict__ AO)
{
    const int bx = blockIdx.x;
    const int h   = bx & 31;
    const int qt  = 31 - (bx >> 5);       // heavy tiles first
    const int hkv = h >> 2;
    const int t = threadIdx.x;
    const int w = t >> 6, l = t & 63;
    const int l16 = l & 15, lk = l >> 4;
    const int q0 = qt * 64 + w * 16;

    __shared__ u16 sK[2][64 * 128];       // kv-major, XOR-swizzled 16B chunks
    __shared__ u16 sV[2][128 * 64];       // d-major (V^T), XOR-swizzled
    __shared__ u16 sP[4 * 1024];          // per-wave 16x64 P tile (row = q)
    u16* sPw = sP + w * 1024;

    auto stageKV = [&](int buf, int kv0) {
#pragma unroll
        for (int p = 0; p < 4; ++p) {
            int P = p * 256 + w * 64 + l;
            int r = P >> 4, pc = P & 15;
            int c = ((pc & 7) ^ (r & 7)) | (pc & 8);
            const u16* g = Km + (size_t)(kv0 + r) * KVS + hkv * 128 + c * 8;
            __builtin_amdgcn_global_load_lds((glb_u8*)g,
                (lds_u8*)(sK[buf] + (size_t)(p * 256 + w * 64) * 8), 16, 0, 0);
        }
#pragma unroll
        for (int p = 0; p < 4; ++p) {
            int P = p * 256 + w * 64 + l;
            int r = P >> 3, pc = P & 7;
            int c = pc ^ (r & 7);
            const u16* g = VT + (size_t)(hkv * 128 + r) * S_LEN + kv0 + c * 8;
            __builtin_amdgcn_global_load_lds((glb_u8*)g,
                (lds_u8*)(sV[buf] + (size_t)(p * 256 + w * 64) * 8), 16, 0, 0);
        }
    };

    bf16x8 qf[4];
#pragma unroll
    for (int kk = 0; kk < 4; ++kk)
        qf[kk] = *(const bf16x8*)(Q + (size_t)(q0 + l16) * QD + h * 128 + kk * 32 + lk * 8);

    bf16x8 vones;
#pragma unroll
    for (int e = 0; e < 8; ++e) vones[e] = (__bf16)1.0f;

    f32x4 o[8] = {};
    f32x4 lacc = {};

    stageKV(0, 0);
    int cur = 0;
    for (int it = 0; it <= qt; ++it) {
        const int kv0 = it * 64;
        __syncthreads();   // buf[cur] resident; prior iteration's reads done
        if (it < qt) stageKV(cur ^ 1, kv0 + 64);
        const u16* cK = sK[cur];
        const u16* cV = sV[cur];

        // ---- QK^T (swapped: A=K rows, B=Q cols) ----
        f32x4 sc[4] = {};
        __builtin_amdgcn_s_setprio(1);
#pragma unroll
        for (int c = 0; c < 4; ++c)
#pragma unroll
            for (int kk = 0; kk < 4; ++kk) {
                int rk = c * 16 + l16;
                int cl = kk * 4 + lk;
                int ph = ((cl & 7) ^ (rk & 7)) | (cl & 8);
                bf16x8 kf = *(const bf16x8*)(cK + rk * 128 + ph * 8);
                sc[c] = __builtin_amdgcn_mfma_f32_16x16x32_bf16(kf, qf[kk], sc[c], 0, 0, 0);
            }
        __builtin_amdgcn_s_setprio(0);
        // lane now holds S[q = q0+l16][kv = kv0 + c*16 + lk*4 + j]

        // ---- P = exp2(t - M2); mask only on the diagonal tile ----
        float p[4][4];
        if (it == qt) {
            const int qrow = q0 + l16;
#pragma unroll
            for (int c = 0; c < 4; ++c)
#pragma unroll
                for (int j = 0; j < 4; ++j) {
                    int kv = kv0 + c * 16 + lk * 4 + j;
                    float v = (kv > qrow) ? -1e30f : (sc[c][j] - M2F);
                    p[c][j] = exp2f(v);
                }
        } else {
#pragma unroll
            for (int c = 0; c < 4; ++c)
#pragma unroll
                for (int j = 0; j < 4; ++j)
                    p[c][j] = exp2f(sc[c][j] - M2F);
        }

        // ---- P -> LDS: row = q (l16), 4 consecutive kv per write (b64) ----
#pragma unroll
        for (int c = 0; c < 4; ++c) {
            u32x2 val;
            val.x = cvt_pk_bf16(p[c][0], p[c][1]);
            val.y = cvt_pk_bf16(p[c][2], p[c][3]);
            int g = (2 * c + (lk >> 1)) ^ (l16 & 7);
            *(u32x2*)(sPw + l16 * 64 + g * 8 + (lk & 1) * 4) = val;
        }
        asm volatile("s_waitcnt lgkmcnt(0)" ::: "memory");
        __builtin_amdgcn_sched_barrier(0);

        bf16x8 af[2];
#pragma unroll
        for (int ks = 0; ks < 2; ++ks)
            af[ks] = *(const bf16x8*)(sPw + l16 * 64 + (((ks * 4 + lk) ^ (l16 & 7)) * 8));

        // ---- PV + ones-MFMA row-sum ----
        __builtin_amdgcn_s_setprio(1);
#pragma unroll
        for (int n = 0; n < 8; ++n) {
#pragma unroll
            for (int ks = 0; ks < 2; ++ks) {
                int rd = n * 16 + l16;
                int cl = ks * 4 + lk;
                int ph = cl ^ (rd & 7);
                bf16x8 vf = *(const bf16x8*)(cV + rd * 64 + ph * 8);
                o[n] = __builtin_amdgcn_mfma_f32_16x16x32_bf16(af[ks], vf, o[n], 0, 0, 0);
            }
        }
#pragma unroll
        for (int ks = 0; ks < 2; ++ks)
            lacc = __builtin_amdgcn_mfma_f32_16x16x32_bf16(af[ks], vones, lacc, 0, 0, 0);
        __builtin_amdgcn_s_setprio(0);
        cur ^= 1;
    }

    float inv[4];
#pragma unroll
    for (int j = 0; j < 4; ++j) inv[j] = __builtin_amdgcn_rcpf(lacc[j]);
#pragma unroll
    for (int n = 0; n < 8; ++n)
#pragma unroll
        for (int j = 0; j < 4; ++j) {
            int row = q0 + lk * 4 + j;
            int col = h * 128 + n * 16 + l16;
            AO[(size_t)row * QD + col] = f2bf(o[n][j] * inv[j]);
        }
}

// ---------------- launch ----------------
extern "C" void kernel_launch(void* const* d_in, const int* in_sizes, int n_in,
                              void* d_out, int out_size, void* d_ws, size_t ws_size,
                              hipStream_t stream) {
    const float* X   = (const float*)d_in[0];     // (S, D) fp32
    const int*   pos = (const int*)d_in[2];       // (1, S) int32
    const float* Wq  = (const float*)d_in[3];     // (D, QD) fp32
    const float* Wk  = (const float*)d_in[4];     // (D, KVD) fp32
    const float* Wv  = (const float*)d_in[5];     // (D, KVD) fp32
    const float* Wo  = (const float*)d_in[6];     // (QD, D) fp32
    float* out = (float*)d_out;                   // (S, D) fp32

    char* ws = (char*)d_ws;
    size_t off = 0;
    auto alloc = [&](size_t bytes) -> void* {
        void* p = ws + off;
        off += (bytes + 255) & ~(size_t)255;
        return p;
    };
    u16* Xb   = (u16*)alloc((size_t)S_LEN * D_MODEL * 2);
    u16* WqT  = (u16*)alloc((size_t)D_MODEL * QD * 2);
    u16* WkvT = (u16*)alloc((size_t)D_MODEL * KVS * 2);   // [WkT; WvT] (2048, 4096)
    u16* WoT  = (u16*)alloc((size_t)QD * D_MODEL * 2);
    u16* Qm   = (u16*)alloc((size_t)S_LEN * QD * 2);
    u16* KVm  = (u16*)alloc((size_t)S_LEN * KVS * 2);     // K | V fused, stride 2048
    u16* VTm  = (u16*)alloc((size_t)KVD * S_LEN * 2);
    u16* AO   = (u16*)alloc((size_t)S_LEN * QD * 2);
    float* ctab = (float*)alloc((size_t)S_LEN * 64 * 4);
    float* stab = (float*)alloc((size_t)S_LEN * 64 * 4);

    // X -> bf16
    {
        int n4 = (S_LEN * D_MODEL) / 4;
        conv_f2b_kernel<<<dim3((n4 + 255) / 256), dim3(256), 0, stream>>>(X, Xb, n4);
    }

    dim3 tb(32, 8);
    // W (K,N) f32 -> WT (N,K) bf16
    transpose_f2b_kernel<<<dim3(QD / 32, D_MODEL / 32), tb, 0, stream>>>(Wq, WqT, D_MODEL, QD);
    transpose_f2b_kernel<<<dim3(KVD / 32, D_MODEL / 32), tb, 0, stream>>>(
        Wk, WkvT, D_MODEL, KVD);
    transpose_f2b_kernel<<<dim3(KVD / 32, D_MODEL / 32), tb, 0, stream>>>(
        Wv, WkvT + (size_t)KVD * D_MODEL, D_MODEL, KVD);
    transpose_f2b_kernel<<<dim3(D_MODEL / 32, QD / 32), tb, 0, stream>>>(Wo, WoT, QD, D_MODEL);

    gemm_wide_kernel<u16><<<dim3((S_LEN / BMW) * (QD / BNW)), dim3(512), 0, stream>>>(
        Xb, WqT, Qm, S_LEN, QD, D_MODEL);
    gemm_bt_kernel<u16><<<dim3((S_LEN / BM) * (KVS / BN)), dim3(256), 0, stream>>>(
        Xb, WkvT, KVm, S_LEN, KVS, D_MODEL);

    rope_table_kernel<<<dim3(S_LEN), dim3(64), 0, stream>>>(pos, ctab, stab);
    rope_apply_q_kernel<<<dim3(S_LEN), dim3(N_HEADS * 32), 0, stream>>>(Qm, ctab, stab);
    rope_apply_k_kernel<<<dim3(S_LEN), dim3(N_KVH * 32), 0, stream>>>(KVm, ctab, stab);

    // V^T from fused KV buffer (V = cols 1024..2047, row stride 2048)
    transpose_kernel<<<dim3(KVD / 32, S_LEN / 32), tb, 0, stream>>>(
        KVm + KVD, VTm, S_LEN, KVD, KVS);

    attn_kernel<<<dim3(32 * 32), dim3(256), 0, stream>>>(Qm, KVm, VTm, AO);

    gemm_wide_kernel<float><<<dim3((S_LEN / BMW) * (D_MODEL / BNW)), dim3(512), 0, stream>>>(
        AO, WoT, out, S_LEN, D_MODEL, QD);
}

// Round 8
// 329.663 us; speedup vs baseline: 1.1561x; 1.1561x over previous
//
#include <hip/hip_runtime.h>
#include <hip/hip_bf16.h>
#include <stdint.h>

typedef uint16_t u16;
typedef __bf16 bf16x8 __attribute__((ext_vector_type(8)));
typedef float f32x4 __attribute__((ext_vector_type(4)));
typedef u16 u16x4 __attribute__((ext_vector_type(4)));
typedef uint32_t u32x2 __attribute__((ext_vector_type(2)));

#define S_LEN 2048
#define D_MODEL 4096
#define N_HEADS 32
#define N_KVH 8
#define HEAD_DIM 128
#define QD 4096   // N_HEADS*HEAD_DIM
#define KVD 1024  // N_KVH*HEAD_DIM
#define NF  6144  // fused N: QD + 2*KVD

// softmax: P = exp2(t - M2), t = (q.k)*scale*log2e (scale*log2e folded into Q)
#define QSC 0.1275253958595506f   // (1/sqrt(128)) * log2(e)
#define M2F 16.0f                 // fixed bound in log2 units; |t| <= ~9

typedef __attribute__((address_space(3))) uint8_t lds_u8;
typedef const __attribute__((address_space(1))) uint8_t glb_u8;

__device__ __forceinline__ float bf2f(u16 x) {
    union { unsigned u; float f; } c; c.u = ((unsigned)x) << 16; return c.f;
}
__device__ __forceinline__ u16 f2bf(float f) {
    union { float f; unsigned u; } c; c.f = f;
    unsigned u = c.u;
    u += 0x7fffu + ((u >> 16) & 1u);
    return (u16)(u >> 16);
}
__device__ __forceinline__ uint32_t cvt_pk_bf16(float a, float b) {
    uint32_t r;
    asm("v_cvt_pk_bf16_f32 %0, %1, %2" : "=v"(r) : "v"(a), "v"(b));
    return r;
}

// ---------------- f32 -> bf16 convert (vectorized x4) ----------------
__global__ __launch_bounds__(256) void conv_f2b_kernel(
    const float* __restrict__ in, u16* __restrict__ out, int n4)
{
    int i = blockIdx.x * blockDim.x + threadIdx.x;
    if (i < n4) {
        float4 v = ((const float4*)in)[i];
        u16x4 o;
        o.x = f2bf(v.x); o.y = f2bf(v.y); o.z = f2bf(v.z); o.w = f2bf(v.w);
        ((u16x4*)out)[i] = o;
    }
}

// ---------------- transpose+convert: in f32 (R,C) -> out bf16 (C,R) ----------------
__global__ __launch_bounds__(256) void transpose_f2b_kernel(
    const float* __restrict__ in, u16* __restrict__ out, int R, int C)
{
    __shared__ u16 tile[32][33];
    const int cb = blockIdx.x * 32;
    const int rb = blockIdx.y * 32;
    const int tx = threadIdx.x;       // 0..31
    const int ty0 = threadIdx.y;      // 0..7
#pragma unroll
    for (int i = 0; i < 4; ++i) {
        int ty = ty0 + i * 8;
        tile[ty][tx] = f2bf(in[(size_t)(rb + ty) * C + cb + tx]);
    }
    __syncthreads();
#pragma unroll
    for (int i = 0; i < 4; ++i) {
        int ty = ty0 + i * 8;
        out[(size_t)(cb + ty) * R + rb + tx] = tile[tx][ty];
    }
}

// ---------------- RoPE cos/sin table: (S,64) fp32 each ----------------
__global__ void rope_table_kernel(const int* __restrict__ pos,
                                  float* __restrict__ ctab, float* __restrict__ stab)
{
    int s = blockIdx.x;
    int i = threadIdx.x; // 0..63
    float p = (float)pos[s];
    float freq = __expf(-(float)i * (9.210340371976184f / 64.0f)); // 10000^(-i/64)
    float ang = p * freq;
    ctab[s * 64 + i] = cosf(ang);
    stab[s * 64 + i] = sinf(ang);
}

// ---------------- fused QKV GEMM: [Q|K|V] = Xb @ [WqT;WkT;WvT]^T ----------------
// 128x128 tile, 2-phase dbuf global_load_lds, XOR-swizzled LDS.
// Epilogue fuses RoPE (rotate pairs live in-lane: acc[m][n] with acc[m][n+2]),
// Q-scale (QSC), and V^T scatter (VTm[d][s]).
#define BM 128
#define BN 128
#define BKK 64

__global__ __launch_bounds__(256) void gemm_qkv_kernel(
    const u16* __restrict__ A, const u16* __restrict__ BT,
    u16* __restrict__ Qm, u16* __restrict__ Km, u16* __restrict__ VTm,
    const float* __restrict__ ctab, const float* __restrict__ stab)
{
    const int M = S_LEN, N = NF, K = D_MODEL;
    __shared__ u16 sA[2][BM * BKK];
    __shared__ u16 sB[2][BN * BKK];
    const int nbx = N / BN;
    const int bx = blockIdx.x % nbx;
    const int by = blockIdx.x / nbx;
    const int row0 = by * BM, col0 = bx * BN;
    const int t = threadIdx.x;
    const int w = t >> 6, l = t & 63;
    const int wr = w >> 1, wc = w & 1;
    const int l16 = l & 15, lk = l >> 4;

    f32x4 acc[4][4] = {};

    auto stage = [&](int buf, int k0) {
#pragma unroll
        for (int j = 0; j < 4; ++j) {
            int chunk = j * 256 + w * 64 + l;
            int r = chunk >> 3;
            int pc = chunk & 7;
            int gch = pc ^ (r & 7);
            const u16* ga = A  + (size_t)(row0 + r) * K + k0 + gch * 8;
            const u16* gb = BT + (size_t)(col0 + r) * K + k0 + gch * 8;
            __builtin_amdgcn_global_load_lds((glb_u8*)ga,
                (lds_u8*)(sA[buf] + (size_t)(j * 256 + w * 64) * 8), 16, 0, 0);
            __builtin_amdgcn_global_load_lds((glb_u8*)gb,
                (lds_u8*)(sB[buf] + (size_t)(j * 256 + w * 64) * 8), 16, 0, 0);
        }
    };

    stage(0, 0);
    int cur = 0;
    for (int k0 = 0; k0 < K; k0 += BKK) {
        __syncthreads();   // buf[cur] resident; prior reads done
        if (k0 + BKK < K) stage(cur ^ 1, k0 + BKK);
        const u16* cA = sA[cur];
        const u16* cB = sB[cur];
#pragma unroll
        for (int kk = 0; kk < 2; ++kk) {
            bf16x8 af[4], bfr[4];
#pragma unroll
            for (int m = 0; m < 4; ++m) {
                int r = wr * 64 + m * 16 + l16;
                int ch = (kk * 4 + lk) ^ (r & 7);
                af[m] = *(const bf16x8*)(cA + r * BKK + ch * 8);
            }
#pragma unroll
            for (int n = 0; n < 4; ++n) {
                int r = wc * 64 + n * 16 + l16;
                int ch = (kk * 4 + lk) ^ (r & 7);
                bfr[n] = *(const bf16x8*)(cB + r * BKK + ch * 8);
            }
            __builtin_amdgcn_s_setprio(1);
#pragma unroll
            for (int m = 0; m < 4; ++m)
#pragma unroll
                for (int n = 0; n < 4; ++n)
                    acc[m][n] = __builtin_amdgcn_mfma_f32_16x16x32_bf16(
                        af[m], bfr[n], acc[m][n], 0, 0, 0);
            __builtin_amdgcn_s_setprio(0);
        }
        cur ^= 1;
    }

    // ---- epilogue: RoPE rotate (first-half blocks of Q/K heads), Q scale, route ----
    const int colbase = col0 + wc * 64;       // multiple of 64
    const bool isQ = colbase < QD;
    const bool isK = !isQ && colbase < QD + KVD;
    const bool doRot = ((colbase & 127) == 0) && (colbase < QD + KVD);

#pragma unroll
    for (int m = 0; m < 4; ++m) {
        const int rbase = row0 + wr * 64 + m * 16 + lk * 4;
        float vv[4][4];
#pragma unroll
        for (int n = 0; n < 4; ++n)
#pragma unroll
            for (int j = 0; j < 4; ++j) vv[n][j] = acc[m][n][j];
        if (doRot) {
#pragma unroll
            for (int n = 0; n < 2; ++n) {
                int d = n * 16 + l16;             // 0..31
#pragma unroll
                for (int j = 0; j < 4; ++j) {
                    int r = rbase + j;
                    float c1 = ctab[r * 64 + d],      s1 = stab[r * 64 + d];
                    float c2 = ctab[r * 64 + d + 32], s2 = stab[r * 64 + d + 32];
                    float a = vv[n][j], b = vv[n + 2][j];
                    vv[n][j]     = a * c1 - b * s1;
                    vv[n + 2][j] = b * c2 + a * s2;
                }
            }
        }
        if (isQ) {
#pragma unroll
            for (int n = 0; n < 4; ++n)
#pragma unroll
                for (int j = 0; j < 4; ++j)
                    Qm[(size_t)(rbase + j) * QD + colbase + n * 16 + l16] =
                        f2bf(vv[n][j] * QSC);
        } else if (isK) {
#pragma unroll
            for (int n = 0; n < 4; ++n)
#pragma unroll
                for (int j = 0; j < 4; ++j)
                    Km[(size_t)(rbase + j) * KVD + (colbase - QD) + n * 16 + l16] =
                        f2bf(vv[n][j]);
        } else {
#pragma unroll
            for (int n = 0; n < 4; ++n)
#pragma unroll
                for (int j = 0; j < 4; ++j)
                    VTm[(size_t)(colbase - QD - KVD + n * 16 + l16) * S_LEN + rbase + j] =
                        f2bf(vv[n][j]);
        }
    }
}

// ---------------- GEMM 128x128: C(M,N) = A(M,K) @ BT(N,K)^T ----------------
template <typename OT>
__global__ __launch_bounds__(256) void gemm_bt_kernel(
    const u16* __restrict__ A, const u16* __restrict__ BT, OT* __restrict__ C,
    int M, int N, int K)
{
    __shared__ u16 sA[2][BM * BKK];
    __shared__ u16 sB[2][BN * BKK];
    const int nbx = N / BN;
    const int bx = blockIdx.x % nbx;
    const int by = blockIdx.x / nbx;
    const int row0 = by * BM, col0 = bx * BN;
    const int t = threadIdx.x;
    const int w = t >> 6, l = t & 63;
    const int wr = w >> 1, wc = w & 1;
    const int l16 = l & 15, lk = l >> 4;

    f32x4 acc[4][4] = {};

    auto stage = [&](int buf, int k0) {
#pragma unroll
        for (int j = 0; j < 4; ++j) {
            int chunk = j * 256 + w * 64 + l;
            int r = chunk >> 3;
            int pc = chunk & 7;
            int gch = pc ^ (r & 7);
            const u16* ga = A  + (size_t)(row0 + r) * K + k0 + gch * 8;
            const u16* gb = BT + (size_t)(col0 + r) * K + k0 + gch * 8;
            __builtin_amdgcn_global_load_lds((glb_u8*)ga,
                (lds_u8*)(sA[buf] + (size_t)(j * 256 + w * 64) * 8), 16, 0, 0);
            __builtin_amdgcn_global_load_lds((glb_u8*)gb,
                (lds_u8*)(sB[buf] + (size_t)(j * 256 + w * 64) * 8), 16, 0, 0);
        }
    };

    stage(0, 0);
    int cur = 0;
    for (int k0 = 0; k0 < K; k0 += BKK) {
        __syncthreads();
        if (k0 + BKK < K) stage(cur ^ 1, k0 + BKK);
        const u16* cA = sA[cur];
        const u16* cB = sB[cur];
#pragma unroll
        for (int kk = 0; kk < 2; ++kk) {
            bf16x8 af[4], bfr[4];
#pragma unroll
            for (int m = 0; m < 4; ++m) {
                int r = wr * 64 + m * 16 + l16;
                int ch = (kk * 4 + lk) ^ (r & 7);
                af[m] = *(const bf16x8*)(cA + r * BKK + ch * 8);
            }
#pragma unroll
            for (int n = 0; n < 4; ++n) {
                int r = wc * 64 + n * 16 + l16;
                int ch = (kk * 4 + lk) ^ (r & 7);
                bfr[n] = *(const bf16x8*)(cB + r * BKK + ch * 8);
            }
            __builtin_amdgcn_s_setprio(1);
#pragma unroll
            for (int m = 0; m < 4; ++m)
#pragma unroll
                for (int n = 0; n < 4; ++n)
                    acc[m][n] = __builtin_amdgcn_mfma_f32_16x16x32_bf16(
                        af[m], bfr[n], acc[m][n], 0, 0, 0);
            __builtin_amdgcn_s_setprio(0);
        }
        cur ^= 1;
    }
#pragma unroll
    for (int m = 0; m < 4; ++m)
#pragma unroll
        for (int n = 0; n < 4; ++n)
#pragma unroll
            for (int j = 0; j < 4; ++j) {
                int row = row0 + wr * 64 + m * 16 + lk * 4 + j;
                int col = col0 + wc * 64 + n * 16 + l16;
                if constexpr (sizeof(OT) == 2)
                    C[(size_t)row * N + col] = f2bf(acc[m][n][j]);
                else
                    C[(size_t)row * N + col] = acc[m][n][j];
            }
}

// ---------------- flash attention ----------------
// 4 waves share one 64-row q-tile; K/V LDS-staged, 2-phase double-buffered.
// Swapped QK, fixed-bound softmax (P=exp2(t-16)), ones-MFMA row-sum.
__global__ __launch_bounds__(256) void attn_kernel(
    const u16* __restrict__ Q, const u16* __restrict__ Km, const u16* __restrict__ VT,
    u16* __restrict__ AO)
{
    const int bx = blockIdx.x;
    const int h   = bx & 31;
    const int qt  = 31 - (bx >> 5);       // heavy tiles first
    const int hkv = h >> 2;
    const int t = threadIdx.x;
    const int w = t >> 6, l = t & 63;
    const int l16 = l & 15, lk = l >> 4;
    const int q0 = qt * 64 + w * 16;

    __shared__ u16 sK[2][64 * 128];       // kv-major, XOR-swizzled 16B chunks
    __shared__ u16 sV[2][128 * 64];       // d-major (V^T), XOR-swizzled
    __shared__ u16 sP[4 * 1024];          // per-wave 16x64 P tile (row = q)
    u16* sPw = sP + w * 1024;

    auto stageKV = [&](int buf, int kv0) {
#pragma unroll
        for (int p = 0; p < 4; ++p) {
            int P = p * 256 + w * 64 + l;
            int r = P >> 4, pc = P & 15;
            int c = ((pc & 7) ^ (r & 7)) | (pc & 8);
            const u16* g = Km + (size_t)(kv0 + r) * KVD + hkv * 128 + c * 8;
            __builtin_amdgcn_global_load_lds((glb_u8*)g,
                (lds_u8*)(sK[buf] + (size_t)(p * 256 + w * 64) * 8), 16, 0, 0);
        }
#pragma unroll
        for (int p = 0; p < 4; ++p) {
            int P = p * 256 + w * 64 + l;
            int r = P >> 3, pc = P & 7;
            int c = pc ^ (r & 7);
            const u16* g = VT + (size_t)(hkv * 128 + r) * S_LEN + kv0 + c * 8;
            __builtin_amdgcn_global_load_lds((glb_u8*)g,
                (lds_u8*)(sV[buf] + (size_t)(p * 256 + w * 64) * 8), 16, 0, 0);
        }
    };

    bf16x8 qf[4];
#pragma unroll
    for (int kk = 0; kk < 4; ++kk)
        qf[kk] = *(const bf16x8*)(Q + (size_t)(q0 + l16) * QD + h * 128 + kk * 32 + lk * 8);

    bf16x8 vones;
#pragma unroll
    for (int e = 0; e < 8; ++e) vones[e] = (__bf16)1.0f;

    f32x4 o[8] = {};
    f32x4 lacc = {};

    stageKV(0, 0);
    int cur = 0;
    for (int it = 0; it <= qt; ++it) {
        const int kv0 = it * 64;
        __syncthreads();   // buf[cur] resident; prior iteration's reads done
        if (it < qt) stageKV(cur ^ 1, kv0 + 64);
        const u16* cK = sK[cur];
        const u16* cV = sV[cur];

        // ---- QK^T (swapped: A=K rows, B=Q cols) ----
        f32x4 sc[4] = {};
        __builtin_amdgcn_s_setprio(1);
#pragma unroll
        for (int c = 0; c < 4; ++c)
#pragma unroll
            for (int kk = 0; kk < 4; ++kk) {
                int rk = c * 16 + l16;
                int cl = kk * 4 + lk;
                int ph = ((cl & 7) ^ (rk & 7)) | (cl & 8);
                bf16x8 kf = *(const bf16x8*)(cK + rk * 128 + ph * 8);
                sc[c] = __builtin_amdgcn_mfma_f32_16x16x32_bf16(kf, qf[kk], sc[c], 0, 0, 0);
            }
        __builtin_amdgcn_s_setprio(0);
        // lane holds S[q = q0+l16][kv = kv0 + c*16 + lk*4 + j]

        // ---- P = exp2(t - M2); mask only on the diagonal tile ----
        float p[4][4];
        if (it == qt) {
            const int qrow = q0 + l16;
#pragma unroll
            for (int c = 0; c < 4; ++c)
#pragma unroll
                for (int j = 0; j < 4; ++j) {
                    int kv = kv0 + c * 16 + lk * 4 + j;
                    float v = (kv > qrow) ? -1e30f : (sc[c][j] - M2F);
                    p[c][j] = exp2f(v);
                }
        } else {
#pragma unroll
            for (int c = 0; c < 4; ++c)
#pragma unroll
                for (int j = 0; j < 4; ++j)
                    p[c][j] = exp2f(sc[c][j] - M2F);
        }

        // ---- P -> LDS: row = q (l16), 4 consecutive kv per write (b64) ----
#pragma unroll
        for (int c = 0; c < 4; ++c) {
            u32x2 val;
            val.x = cvt_pk_bf16(p[c][0], p[c][1]);
            val.y = cvt_pk_bf16(p[c][2], p[c][3]);
            int g = (2 * c + (lk >> 1)) ^ (l16 & 7);
            *(u32x2*)(sPw + l16 * 64 + g * 8 + (lk & 1) * 4) = val;
        }
        asm volatile("s_waitcnt lgkmcnt(0)" ::: "memory");
        __builtin_amdgcn_sched_barrier(0);

        bf16x8 af[2];
#pragma unroll
        for (int ks = 0; ks < 2; ++ks)
            af[ks] = *(const bf16x8*)(sPw + l16 * 64 + (((ks * 4 + lk) ^ (l16 & 7)) * 8));

        // ---- PV + ones-MFMA row-sum ----
        __builtin_amdgcn_s_setprio(1);
#pragma unroll
        for (int n = 0; n < 8; ++n) {
#pragma unroll
            for (int ks = 0; ks < 2; ++ks) {
                int rd = n * 16 + l16;
                int cl = ks * 4 + lk;
                int ph = cl ^ (rd & 7);
                bf16x8 vf = *(const bf16x8*)(cV + rd * 64 + ph * 8);
                o[n] = __builtin_amdgcn_mfma_f32_16x16x32_bf16(af[ks], vf, o[n], 0, 0, 0);
            }
        }
#pragma unroll
        for (int ks = 0; ks < 2; ++ks)
            lacc = __builtin_amdgcn_mfma_f32_16x16x32_bf16(af[ks], vones, lacc, 0, 0, 0);
        __builtin_amdgcn_s_setprio(0);
        cur ^= 1;
    }

    float inv[4];
#pragma unroll
    for (int j = 0; j < 4; ++j) inv[j] = __builtin_amdgcn_rcpf(lacc[j]);
#pragma unroll
    for (int n = 0; n < 8; ++n)
#pragma unroll
        for (int j = 0; j < 4; ++j) {
            int row = q0 + lk * 4 + j;
            int col = h * 128 + n * 16 + l16;
            AO[(size_t)row * QD + col] = f2bf(o[n][j] * inv[j]);
        }
}

// ---------------- launch ----------------
extern "C" void kernel_launch(void* const* d_in, const int* in_sizes, int n_in,
                              void* d_out, int out_size, void* d_ws, size_t ws_size,
                              hipStream_t stream) {
    const float* X   = (const float*)d_in[0];     // (S, D) fp32
    const int*   pos = (const int*)d_in[2];       // (1, S) int32
    const float* Wq  = (const float*)d_in[3];     // (D, QD) fp32
    const float* Wk  = (const float*)d_in[4];     // (D, KVD) fp32
    const float* Wv  = (const float*)d_in[5];     // (D, KVD) fp32
    const float* Wo  = (const float*)d_in[6];     // (QD, D) fp32
    float* out = (float*)d_out;                   // (S, D) fp32

    char* ws = (char*)d_ws;
    size_t off = 0;
    auto alloc = [&](size_t bytes) -> void* {
        void* p = ws + off;
        off += (bytes + 255) & ~(size_t)255;
        return p;
    };
    u16* Xb  = (u16*)alloc((size_t)S_LEN * D_MODEL * 2);
    u16* WfT = (u16*)alloc((size_t)NF * D_MODEL * 2);     // [WqT; WkT; WvT] (6144, 4096)
    u16* WoT = (u16*)alloc((size_t)QD * D_MODEL * 2);
    u16* Qm  = (u16*)alloc((size_t)S_LEN * QD * 2);
    u16* Km  = (u16*)alloc((size_t)S_LEN * KVD * 2);      // K only, stride 1024
    u16* VTm = (u16*)alloc((size_t)KVD * S_LEN * 2);
    u16* AO  = (u16*)alloc((size_t)S_LEN * QD * 2);
    float* ctab = (float*)alloc((size_t)S_LEN * 64 * 4);
    float* stab = (float*)alloc((size_t)S_LEN * 64 * 4);

    // X -> bf16
    {
        int n4 = (S_LEN * D_MODEL) / 4;
        conv_f2b_kernel<<<dim3((n4 + 255) / 256), dim3(256), 0, stream>>>(X, Xb, n4);
    }

    dim3 tb(32, 8);
    // W (K,N) f32 -> WT (N,K) bf16, packed into WfT rows [Q | K | V]
    transpose_f2b_kernel<<<dim3(QD / 32, D_MODEL / 32), tb, 0, stream>>>(
        Wq, WfT, D_MODEL, QD);
    transpose_f2b_kernel<<<dim3(KVD / 32, D_MODEL / 32), tb, 0, stream>>>(
        Wk, WfT + (size_t)QD * D_MODEL, D_MODEL, KVD);
    transpose_f2b_kernel<<<dim3(KVD / 32, D_MODEL / 32), tb, 0, stream>>>(
        Wv, WfT + (size_t)(QD + KVD) * D_MODEL, D_MODEL, KVD);
    transpose_f2b_kernel<<<dim3(D_MODEL / 32, QD / 32), tb, 0, stream>>>(
        Wo, WoT, QD, D_MODEL);

    rope_table_kernel<<<dim3(S_LEN), dim3(64), 0, stream>>>(pos, ctab, stab);

    // fused QKV projection + RoPE + Q-scale + V^T
    gemm_qkv_kernel<<<dim3((S_LEN / BM) * (NF / BN)), dim3(256), 0, stream>>>(
        Xb, WfT, Qm, Km, VTm, ctab, stab);

    attn_kernel<<<dim3(32 * 32), dim3(256), 0, stream>>>(Qm, Km, VTm, AO);

    gemm_bt_kernel<float><<<dim3((S_LEN / BM) * (D_MODEL / BN)), dim3(256), 0, stream>>>(
        AO, WoT, out, S_LEN, D_MODEL, QD);
}